// Round 1
// 67.218 us; speedup vs baseline: 1.0294x; 1.0294x over previous
//
#include <hip/hip_runtime.h>

// out[i, 0:512]  = 2*X[i]                         (i < 64)
//                = X[i] + sum_{j=i-64}^{i-1} X[j] (i >= 64)
// out[i,512:1024]= X[i]
//
// Fused single kernel: block = (64-row output group g) x (16 float4 cols).
// Stage rows [64g-64, 64g+64) x 16 cols into LDS (32 KB), build 8-row chunk
// sums during staging, then per-thread 8-row sliding window from LDS.
// No workspace, no second dispatch. Grid = 64 x 8 = 512 blocks (2/CU).

#define LENS 64
#define C4   128   // float4 columns per X row (512 floats)
#define CS   16    // float4 columns per block
#define NT   128   // threads per block (2 waves)

__global__ __launch_bounds__(NT) void fused_win_kernel(const float4* __restrict__ X4,
                                                       float4* __restrict__ O4) {
    __shared__ float4 raw[128][CS];  // rows [R0, R0+128) of this block's columns
    __shared__ float4 chk[16][CS];   // 8-row chunk sums of those rows

    const int g   = blockIdx.x;          // 64-row output group
    const int c4b = blockIdx.y * CS;     // column base
    const int tid = threadIdx.x;
    const int c   = tid & (CS - 1);

    if (g == 0) {
        // rows 0..63: H = 2X, second half = X. No LDS, no barrier (whole block).
        const int q = tid >> 4;          // 0..7
#pragma unroll
        for (int k = 0; k < 8; ++k) {
            const int i = q * 8 + k;
            const float4 x = X4[(size_t)i * C4 + c4b + c];
            O4[(size_t)i * (2 * C4) + c4b + c] =
                make_float4(2.f * x.x, 2.f * x.y, 2.f * x.z, 2.f * x.w);
            O4[(size_t)i * (2 * C4) + C4 + c4b + c] = x;
        }
        return;
    }

    const int R0 = g * 64 - LENS;        // first staged row

    // ---- stage rows [R0, R0+128) and build chunk sums (thread: chunks k, k+8)
    {
        const int k = tid >> 4;          // 0..7
#pragma unroll
        for (int kk = 0; kk < 2; ++kk) {
            const int ch = k + kk * 8;   // chunk 0..15
            const float4* gp = X4 + (size_t)(R0 + ch * 8) * C4 + c4b + c;
            float4 s = make_float4(0.f, 0.f, 0.f, 0.f);
#pragma unroll
            for (int j = 0; j < 8; ++j) {
                const float4 x = gp[(size_t)j * C4];
                raw[ch * 8 + j][c] = x;
                s.x += x.x; s.y += x.y; s.z += x.z; s.w += x.w;
            }
            chk[ch][c] = s;
        }
    }
    __syncthreads();

    // ---- slide: thread (q, c) produces rows [64g + 8q, 64g + 8q + 8)
    const int q  = tid >> 4;             // 0..7
    const int i0 = g * 64 + q * 8;

    // initial window [i0-64, i0) = local chunks q .. q+7
    float4 w = make_float4(0.f, 0.f, 0.f, 0.f);
#pragma unroll
    for (int r = 0; r < 8; ++r) {
        const float4 cs = chk[q + r][c];
        w.x += cs.x; w.y += cs.y; w.z += cs.z; w.w += cs.w;
    }

    // rows that leave the window during the slide: local rows [8q, 8q+7)
    float4 hist[7];
#pragma unroll
    for (int j = 0; j < 7; ++j) hist[j] = raw[q * 8 + j][c];

#pragma unroll
    for (int k = 0; k < 8; ++k) {
        const float4 x = raw[64 + q * 8 + k][c];   // X[i0+k]
        O4[(size_t)(i0 + k) * (2 * C4) + c4b + c] =
            make_float4(x.x + w.x, x.y + w.y, x.z + w.z, x.w + w.w);
        O4[(size_t)(i0 + k) * (2 * C4) + C4 + c4b + c] = x;
        if (k < 7) {
            const float4 old = hist[k];
            w.x += x.x - old.x;
            w.y += x.y - old.y;
            w.z += x.z - old.z;
            w.w += x.w - old.w;
        }
    }
}

extern "C" void kernel_launch(void* const* d_in, const int* in_sizes, int n_in,
                              void* d_out, int out_size, void* d_ws, size_t ws_size,
                              hipStream_t stream) {
    const float* X = (const float*)d_in[0];   // (N, 512) fp32; d_in[1]=W is dead code
    float* O = (float*)d_out;                 // (N, 1024) fp32

    const int D = 512;
    const int N = in_sizes[0] / D;            // 4096

    dim3 grid(N / 64, C4 / CS);               // (64, 8) = 512 blocks
    fused_win_kernel<<<grid, NT, 0, stream>>>((const float4*)X, (float4*)O);
}

// Round 3
// 67.042 us; speedup vs baseline: 1.0321x; 1.0026x over previous
//
#include <hip/hip_runtime.h>

// out[i, 0:512]  = 2*X[i]                         (i < 64)
//                = X[i] + sum_{j=i-64}^{i-1} X[j] (i >= 64)
// out[i,512:1024]= X[i]
//
// Fused single kernel: block = (64-row output group g) x (16 float4 cols),
// 256 threads (4 waves), 4 output rows per thread. Stage rows
// [64g-64, 64g+64) x 16 cols into LDS (32 KB) + 4-row chunk sums (8 KB),
// then per-thread 4-row sliding window from LDS.
// Grid = 64 x 8 = 512 blocks -> 2048 waves = 2 waves/SIMD (was 1).

#define LENS 64
#define C4   128   // float4 columns per X row (512 floats)
#define CS   16    // float4 columns per block
#define NT   256   // threads per block (4 waves)

__global__ __launch_bounds__(NT) void fused_win_kernel(const float4* __restrict__ X4,
                                                       float4* __restrict__ O4) {
    __shared__ float4 raw[128][CS];  // rows [R0, R0+128) of this block's columns
    __shared__ float4 chk[32][CS];   // 4-row chunk sums of those rows

    const int g   = blockIdx.x;          // 64-row output group
    const int c4b = blockIdx.y * CS;     // column base
    const int tid = threadIdx.x;
    const int c   = tid & (CS - 1);
    const int q   = tid >> 4;            // 0..15

    if (g == 0) {
        // rows 0..63: H = 2X, second half = X. No LDS, no barrier (whole block).
#pragma unroll
        for (int k = 0; k < 4; ++k) {
            const int i = q * 4 + k;
            const float4 x = X4[(size_t)i * C4 + c4b + c];
            O4[(size_t)i * (2 * C4) + c4b + c] =
                make_float4(2.f * x.x, 2.f * x.y, 2.f * x.z, 2.f * x.w);
            O4[(size_t)i * (2 * C4) + C4 + c4b + c] = x;
        }
        return;
    }

    const int R0 = g * 64 - LENS;        // first staged row

    // ---- stage 8 rows (thread: 4-row chunks 2q, 2q+1) and build chunk sums
    {
        const float4* gp = X4 + (size_t)(R0 + q * 8) * C4 + c4b + c;
#pragma unroll
        for (int h = 0; h < 2; ++h) {
            float4 s = make_float4(0.f, 0.f, 0.f, 0.f);
#pragma unroll
            for (int j = 0; j < 4; ++j) {
                const float4 x = gp[(size_t)(h * 4 + j) * C4];
                raw[q * 8 + h * 4 + j][c] = x;
                s.x += x.x; s.y += x.y; s.z += x.z; s.w += x.w;
            }
            chk[2 * q + h][c] = s;
        }
    }
    __syncthreads();

    // ---- slide: thread (q, c) produces rows [64g + 4q, 64g + 4q + 4)
    const int i0 = g * 64 + q * 4;

    // initial window [i0-64, i0) = local rows [4q, 4q+64) = chunk4 [q, q+16)
    float4 w = make_float4(0.f, 0.f, 0.f, 0.f);
#pragma unroll
    for (int r = 0; r < 16; ++r) {
        const float4 cs = chk[q + r][c];
        w.x += cs.x; w.y += cs.y; w.z += cs.z; w.w += cs.w;
    }

    // rows that leave the window during the slide: local rows [4q, 4q+3)
    float4 hist[3];
#pragma unroll
    for (int j = 0; j < 3; ++j) hist[j] = raw[q * 4 + j][c];

#pragma unroll
    for (int k = 0; k < 4; ++k) {
        const float4 x = raw[64 + q * 4 + k][c];   // X[i0+k]
        O4[(size_t)(i0 + k) * (2 * C4) + c4b + c] =
            make_float4(x.x + w.x, x.y + w.y, x.z + w.z, x.w + w.w);
        O4[(size_t)(i0 + k) * (2 * C4) + C4 + c4b + c] = x;
        if (k < 3) {
            const float4 old = hist[k];
            w.x += x.x - old.x;
            w.y += x.y - old.y;
            w.z += x.z - old.z;
            w.w += x.w - old.w;
        }
    }
}

extern "C" void kernel_launch(void* const* d_in, const int* in_sizes, int n_in,
                              void* d_out, int out_size, void* d_ws, size_t ws_size,
                              hipStream_t stream) {
    const float* X = (const float*)d_in[0];   // (N, 512) fp32; d_in[1]=W is dead code
    float* O = (float*)d_out;                 // (N, 1024) fp32

    const int D = 512;
    const int N = in_sizes[0] / D;            // 4096

    dim3 grid(N / 64, C4 / CS);               // (64, 8) = 512 blocks
    fused_win_kernel<<<grid, NT, 0, stream>>>((const float4*)X, (float4*)O);
}